// Round 1
// baseline (1014.633 us; speedup 1.0000x reference)
//
#include <hip/hip_runtime.h>
#include <cstdint>
#include <cstddef>

// EarthAttention3D (Pangu-Weather): NW=720 windows, L=144 tokens, DIM=192, H=6, hd=32
// fp32 correctness-first baseline. 3 kernels:
//   A: qkv = x @ w1^T + b1  -> q,k,v [w][h][l][d] (q pre-scaled by hd^-0.5)
//   B: per (w,h): S = K.Q^T + bias(i,j) + mask; softmax over j; O = P^T.V -> ao [w][l][h*32+d]
//   C: out = ao @ w2^T + b2
// pos(i,j) = 828*(z_i+2*z_j) + 23*(h_i+6*h_j) + (w_i - w_j + 11), i=(z*6+h)*12+w decomp.
// bias element = bias_table[pos*1440 + tow*6 + h], tow = w % 240.

constexpr int kNW    = 720;
constexpr int kL     = 144;
constexpr int kDim   = 192;
constexpr int kHeads = 6;
constexpr int kHd    = 32;
constexpr float kScale = 0.17677669529663687f;  // 32^-0.5
constexpr size_t kQKVElems = (size_t)kNW * kHeads * kL * kHd;  // 19,906,560

// ---------------------------------------------------------------------------
// Kernel A: QKV projection GEMM. M=103680, K=192, N=576.
// Tile 128(M) x 64(N), K-chunks of 64. 256 threads, 8x4 acc per thread.
// ---------------------------------------------------------------------------
__global__ __launch_bounds__(256) void qkv_kernel(
    const float* __restrict__ x, const float* __restrict__ w1,
    const float* __restrict__ b1, float* __restrict__ q,
    float* __restrict__ k, float* __restrict__ v)
{
  __shared__ __align__(16) float Xs[64][132];  // [k][m], padded
  __shared__ __align__(16) float Ws[64][68];   // [k][n], padded
  const int mt = blockIdx.x / 9;
  const int nt = blockIdx.x % 9;
  const int row0 = mt * 128;
  const int col0 = nt * 64;
  const int tid = threadIdx.x;
  const int tx = tid & 15;    // N-dir (compute) / k-quad (load)
  const int ty = tid >> 4;    // M-dir (compute) / row (load)

  float acc[8][4];
#pragma unroll
  for (int a = 0; a < 8; ++a)
#pragma unroll
    for (int b = 0; b < 4; ++b) acc[a][b] = 0.f;

  for (int kc = 0; kc < 192; kc += 64) {
    // load X chunk 128 rows x 64 k, transposed into LDS
#pragma unroll
    for (int rr = 0; rr < 128; rr += 16) {
      const int r = rr + ty;
      float4 xv = *(const float4*)&x[(size_t)(row0 + r) * 192 + kc + tx * 4];
      Xs[tx * 4 + 0][r] = xv.x; Xs[tx * 4 + 1][r] = xv.y;
      Xs[tx * 4 + 2][r] = xv.z; Xs[tx * 4 + 3][r] = xv.w;
    }
    // load W1 chunk 64 cols x 64 k, transposed
#pragma unroll
    for (int cc = 0; cc < 64; cc += 16) {
      const int c = cc + ty;
      float4 wv = *(const float4*)&w1[(size_t)(col0 + c) * 192 + kc + tx * 4];
      Ws[tx * 4 + 0][c] = wv.x; Ws[tx * 4 + 1][c] = wv.y;
      Ws[tx * 4 + 2][c] = wv.z; Ws[tx * 4 + 3][c] = wv.w;
    }
    __syncthreads();
#pragma unroll 4
    for (int kz = 0; kz < 64; ++kz) {
      float4 a0 = *(const float4*)&Xs[kz][ty * 4];
      float4 a1 = *(const float4*)&Xs[kz][64 + ty * 4];
      float4 bb = *(const float4*)&Ws[kz][tx * 4];
      float av[8] = {a0.x, a0.y, a0.z, a0.w, a1.x, a1.y, a1.z, a1.w};
      float bv[4] = {bb.x, bb.y, bb.z, bb.w};
#pragma unroll
      for (int mi = 0; mi < 8; ++mi)
#pragma unroll
        for (int ni = 0; ni < 4; ++ni) acc[mi][ni] += av[mi] * bv[ni];
    }
    __syncthreads();
  }

  // epilogue: add bias, scatter to q/k/v [w][h][l][d]; 4 cols share (t,h,d0)
  const int col = col0 + tx * 4;
  const int t = col / 192;
  const int rem = col % 192;
  const int h = rem >> 5;
  const int d0 = rem & 31;
  float* dst = (t == 0) ? q : (t == 1) ? k : v;
  const float sc = (t == 0) ? kScale : 1.0f;
  const float4 bvec = make_float4(b1[col], b1[col + 1], b1[col + 2], b1[col + 3]);
#pragma unroll
  for (int mi = 0; mi < 8; ++mi) {
    const int row = row0 + (mi < 4 ? ty * 4 + mi : 64 + ty * 4 + (mi - 4));
    const int w = row / 144;
    const int l = row % 144;
    float4 o;
    o.x = (acc[mi][0] + bvec.x) * sc;
    o.y = (acc[mi][1] + bvec.y) * sc;
    o.z = (acc[mi][2] + bvec.z) * sc;
    o.w = (acc[mi][3] + bvec.w) * sc;
    *(float4*)&dst[(((size_t)(w * 6 + h)) * 144 + l) * 32 + d0] = o;
  }
}

// ---------------------------------------------------------------------------
// Kernel B: fused attention per (window, head). 576 threads (9 waves).
// S stored transposed: S[j][i]. Softmax over j per column i (lane-coalesced).
// ---------------------------------------------------------------------------
__global__ __launch_bounds__(576, 1) void attn_kernel(
    const float* __restrict__ q, const float* __restrict__ k,
    const float* __restrict__ v, const float* __restrict__ mask,
    const float* __restrict__ bt, float* __restrict__ ao)
{
  __shared__ __align__(16) float Qs[32][148];   // [d][i]
  __shared__ __align__(16) float Ks[32][148];   // [d][j]
  __shared__ __align__(16) float Vs[144][36];   // [j][d]
  __shared__ __align__(16) float S[144][148];   // [j][i]
  __shared__ float Sinv[144];

  const int w = blockIdx.x / 6;
  const int h = blockIdx.x % 6;
  const int tid = threadIdx.x;
  const int tow = w % 240;
  const int bth = tow * 6 + h;  // offset within a table row-group
  const size_t qkvbase = ((size_t)(w * 6 + h)) * 144 * 32;
  const float* mrow = mask + (size_t)w * (144 * 144);

  // --- load Q,K (transposed) and V into LDS ---
  for (int f = tid; f < 1152; f += 576) {
    const int l = f >> 3;
    const int d0 = (f & 7) << 2;
    float4 qv = *(const float4*)&q[qkvbase + l * 32 + d0];
    Qs[d0 + 0][l] = qv.x; Qs[d0 + 1][l] = qv.y;
    Qs[d0 + 2][l] = qv.z; Qs[d0 + 3][l] = qv.w;
    float4 kv = *(const float4*)&k[qkvbase + l * 32 + d0];
    Ks[d0 + 0][l] = kv.x; Ks[d0 + 1][l] = kv.y;
    Ks[d0 + 2][l] = kv.z; Ks[d0 + 3][l] = kv.w;
    float4 vv = *(const float4*)&v[qkvbase + l * 32 + d0];
    *(float4*)&Vs[l][d0] = vv;
  }
  __syncthreads();

  // --- S phase: 36x36 grid of 4x4 tiles = 1296 tiles over 576 threads ---
  for (int tile = tid; tile < 1296; tile += 576) {
    const int it = tile % 36;
    const int jt = tile / 36;
    const int i0 = it * 4;
    const int j0 = jt * 4;
    float sacc[4][4];
#pragma unroll
    for (int a = 0; a < 4; ++a)
#pragma unroll
      for (int b = 0; b < 4; ++b) sacc[a][b] = 0.f;
#pragma unroll 4
    for (int d = 0; d < 32; ++d) {
      float4 qv = *(const float4*)&Qs[d][i0];
      float4 kv = *(const float4*)&Ks[d][j0];
      float qa[4] = {qv.x, qv.y, qv.z, qv.w};
      float ka[4] = {kv.x, kv.y, kv.z, kv.w};
#pragma unroll
      for (int jj = 0; jj < 4; ++jj)
#pragma unroll
        for (int ii = 0; ii < 4; ++ii) sacc[jj][ii] += ka[jj] * qa[ii];
    }
    // bias + mask epilogue
    float sv[4][4];  // [jj][ii]
#pragma unroll
    for (int ii = 0; ii < 4; ++ii) {
      const int i = i0 + ii;
      const int wi = i % 12;
      const int hi = (i / 12) % 6;
      const int zi = i / 72;
      const int ibase = 828 * zi + 23 * hi + wi + 11;
      float4 mv = *(const float4*)&mrow[i * 144 + j0];
      float ma[4] = {mv.x, mv.y, mv.z, mv.w};
#pragma unroll
      for (int jj = 0; jj < 4; ++jj) {
        const int j = j0 + jj;
        const int wj = j % 12;
        const int hj = (j / 12) % 6;
        const int zj = j / 72;
        const int pos = ibase + 1656 * zj + 138 * hj - wj;  // 828*2, 23*6
        sv[jj][ii] = sacc[jj][ii] + bt[(size_t)pos * 1440 + bth] + ma[jj];
      }
    }
#pragma unroll
    for (int jj = 0; jj < 4; ++jj)
      *(float4*)&S[j0 + jj][i0] = make_float4(sv[jj][0], sv[jj][1], sv[jj][2], sv[jj][3]);
  }
  __syncthreads();

  // --- softmax over j for each column i; fold 1/sum into epilogue ---
  if (tid < 144) {
    const int i = tid;
    float m = -1e30f;
    for (int j = 0; j < 144; ++j) m = fmaxf(m, S[j][i]);
    float s = 0.f;
    for (int j = 0; j < 144; ++j) {
      float e = __expf(S[j][i] - m);
      S[j][i] = e;
      s += e;
    }
    Sinv[i] = 1.0f / s;
  }
  __syncthreads();

  // --- PV: O[i][d] = sum_j P[j][i] * V[j][d]; 72x8 grid of 2x4 tiles ---
  const int td = tid & 7;
  const int ti2 = tid >> 3;  // 0..71
  const int oi0 = ti2 * 2;
  const int od0 = td * 4;
  float oacc[2][4];
#pragma unroll
  for (int a = 0; a < 2; ++a)
#pragma unroll
    for (int b = 0; b < 4; ++b) oacc[a][b] = 0.f;
#pragma unroll 4
  for (int j = 0; j < 144; ++j) {
    float2 pv = *(const float2*)&S[j][oi0];
    float4 vv = *(const float4*)&Vs[j][od0];
    float pa[2] = {pv.x, pv.y};
    float va[4] = {vv.x, vv.y, vv.z, vv.w};
#pragma unroll
    for (int ii = 0; ii < 2; ++ii)
#pragma unroll
      for (int dd = 0; dd < 4; ++dd) oacc[ii][dd] += pa[ii] * va[dd];
  }
#pragma unroll
  for (int ii = 0; ii < 2; ++ii) {
    const int i = oi0 + ii;
    const float inv = Sinv[i];
    float4 o = make_float4(oacc[ii][0] * inv, oacc[ii][1] * inv,
                           oacc[ii][2] * inv, oacc[ii][3] * inv);
    *(float4*)&ao[((size_t)(w * 144 + i)) * 192 + h * 32 + od0] = o;
  }
}

// ---------------------------------------------------------------------------
// Kernel C: output projection. M=103680, K=192, N=192. Same structure as A.
// ---------------------------------------------------------------------------
__global__ __launch_bounds__(256) void proj_kernel(
    const float* __restrict__ xin, const float* __restrict__ w2,
    const float* __restrict__ b2, float* __restrict__ out)
{
  __shared__ __align__(16) float Xs[64][132];
  __shared__ __align__(16) float Ws[64][68];
  const int mt = blockIdx.x / 3;
  const int nt = blockIdx.x % 3;
  const int row0 = mt * 128;
  const int col0 = nt * 64;
  const int tid = threadIdx.x;
  const int tx = tid & 15;
  const int ty = tid >> 4;

  float acc[8][4];
#pragma unroll
  for (int a = 0; a < 8; ++a)
#pragma unroll
    for (int b = 0; b < 4; ++b) acc[a][b] = 0.f;

  for (int kc = 0; kc < 192; kc += 64) {
#pragma unroll
    for (int rr = 0; rr < 128; rr += 16) {
      const int r = rr + ty;
      float4 xv = *(const float4*)&xin[(size_t)(row0 + r) * 192 + kc + tx * 4];
      Xs[tx * 4 + 0][r] = xv.x; Xs[tx * 4 + 1][r] = xv.y;
      Xs[tx * 4 + 2][r] = xv.z; Xs[tx * 4 + 3][r] = xv.w;
    }
#pragma unroll
    for (int cc = 0; cc < 64; cc += 16) {
      const int c = cc + ty;
      float4 wv = *(const float4*)&w2[(size_t)(col0 + c) * 192 + kc + tx * 4];
      Ws[tx * 4 + 0][c] = wv.x; Ws[tx * 4 + 1][c] = wv.y;
      Ws[tx * 4 + 2][c] = wv.z; Ws[tx * 4 + 3][c] = wv.w;
    }
    __syncthreads();
#pragma unroll 4
    for (int kz = 0; kz < 64; ++kz) {
      float4 a0 = *(const float4*)&Xs[kz][ty * 4];
      float4 a1 = *(const float4*)&Xs[kz][64 + ty * 4];
      float4 bb = *(const float4*)&Ws[kz][tx * 4];
      float av[8] = {a0.x, a0.y, a0.z, a0.w, a1.x, a1.y, a1.z, a1.w};
      float bv[4] = {bb.x, bb.y, bb.z, bb.w};
#pragma unroll
      for (int mi = 0; mi < 8; ++mi)
#pragma unroll
        for (int ni = 0; ni < 4; ++ni) acc[mi][ni] += av[mi] * bv[ni];
    }
    __syncthreads();
  }

  const int col = col0 + tx * 4;
  const float4 bvec = make_float4(b2[col], b2[col + 1], b2[col + 2], b2[col + 3]);
#pragma unroll
  for (int mi = 0; mi < 8; ++mi) {
    const int row = row0 + (mi < 4 ? ty * 4 + mi : 64 + ty * 4 + (mi - 4));
    float4 o = make_float4(acc[mi][0] + bvec.x, acc[mi][1] + bvec.y,
                           acc[mi][2] + bvec.z, acc[mi][3] + bvec.w);
    *(float4*)&out[(size_t)row * 192 + col] = o;
  }
}

// ---------------------------------------------------------------------------
extern "C" void kernel_launch(void* const* d_in, const int* in_sizes, int n_in,
                              void* d_out, int out_size, void* d_ws, size_t ws_size,
                              hipStream_t stream)
{
  const float* x    = (const float*)d_in[0];  // (720,144,192)
  const float* mask = (const float*)d_in[1];  // (720,144,144)
  const float* w1   = (const float*)d_in[2];  // (576,192)
  const float* b1   = (const float*)d_in[3];  // (576,)
  const float* w2   = (const float*)d_in[4];  // (192,192)
  const float* b2   = (const float*)d_in[5];  // (192,)
  const float* bt   = (const float*)d_in[6];  // (3312,240,6)
  float* out = (float*)d_out;

  float* q  = (float*)d_ws;
  float* k  = q + kQKVElems;
  float* v  = k + kQKVElems;
  float* ao = v + kQKVElems;  // [w][l][192]

  qkv_kernel<<<810 * 9, 256, 0, stream>>>(x, w1, b1, q, k, v);
  attn_kernel<<<kNW * kHeads, 576, 0, stream>>>(q, k, v, mask, bt, ao);
  proj_kernel<<<810 * 3, 256, 0, stream>>>(ao, w2, b2, out);
}

// Round 2
// 822.621 us; speedup vs baseline: 1.2334x; 1.2334x over previous
//
#include <hip/hip_runtime.h>
#include <cstdint>
#include <cstddef>

// EarthAttention3D (Pangu-Weather): NW=720 windows, L=144 tokens, DIM=192, H=6, hd=32
// fp32, 3 kernels:
//   A: qkv = x @ w1^T + b1  -> q,k,v [w][h][l][d] (q pre-scaled by hd^-0.5)
//   B: per (w,h): S = K.Q^T + bias(i,j) + mask; softmax over j; O = P^T.V -> ao [w][l][192]
//   C: out = ao @ w2^T + b2
// pos(i,j) = 828*z_i + 23*h_i + w_i + 11 + 1656*z_j + 138*h_j - w_j, i=(z*6+h)*12+w.
// bias element = bias_table[pos*1440 + tow*6 + h], tow = w % 240. Range of pos: [0,3312).

constexpr int kNW    = 720;
constexpr float kScale = 0.17677669529663687f;  // 32^-0.5
constexpr size_t kQKVElems = (size_t)kNW * 6 * 144 * 32;  // 19,906,560

// ---------------------------------------------------------------------------
// Kernel A: QKV projection GEMM. M=103680, K=192, N=576.
// Tile 128(M) x 64(N), K-chunks of 64. 256 threads, 8x4 acc per thread.
// ---------------------------------------------------------------------------
__global__ __launch_bounds__(256) void qkv_kernel(
    const float* __restrict__ x, const float* __restrict__ w1,
    const float* __restrict__ b1, float* __restrict__ q,
    float* __restrict__ k, float* __restrict__ v)
{
  __shared__ __align__(16) float Xs[64][132];  // [k][m], padded
  __shared__ __align__(16) float Ws[64][68];   // [k][n], padded
  const int mt = blockIdx.x / 9;
  const int nt = blockIdx.x % 9;
  const int row0 = mt * 128;
  const int col0 = nt * 64;
  const int tid = threadIdx.x;
  const int tx = tid & 15;
  const int ty = tid >> 4;

  float acc[8][4];
#pragma unroll
  for (int a = 0; a < 8; ++a)
#pragma unroll
    for (int b = 0; b < 4; ++b) acc[a][b] = 0.f;

  for (int kc = 0; kc < 192; kc += 64) {
#pragma unroll
    for (int rr = 0; rr < 128; rr += 16) {
      const int r = rr + ty;
      float4 xv = *(const float4*)&x[(size_t)(row0 + r) * 192 + kc + tx * 4];
      Xs[tx * 4 + 0][r] = xv.x; Xs[tx * 4 + 1][r] = xv.y;
      Xs[tx * 4 + 2][r] = xv.z; Xs[tx * 4 + 3][r] = xv.w;
    }
#pragma unroll
    for (int cc = 0; cc < 64; cc += 16) {
      const int c = cc + ty;
      float4 wv = *(const float4*)&w1[(size_t)(col0 + c) * 192 + kc + tx * 4];
      Ws[tx * 4 + 0][c] = wv.x; Ws[tx * 4 + 1][c] = wv.y;
      Ws[tx * 4 + 2][c] = wv.z; Ws[tx * 4 + 3][c] = wv.w;
    }
    __syncthreads();
#pragma unroll 4
    for (int kz = 0; kz < 64; ++kz) {
      float4 a0 = *(const float4*)&Xs[kz][ty * 4];
      float4 a1 = *(const float4*)&Xs[kz][64 + ty * 4];
      float4 bb = *(const float4*)&Ws[kz][tx * 4];
      float av[8] = {a0.x, a0.y, a0.z, a0.w, a1.x, a1.y, a1.z, a1.w};
      float bv[4] = {bb.x, bb.y, bb.z, bb.w};
#pragma unroll
      for (int mi = 0; mi < 8; ++mi)
#pragma unroll
        for (int ni = 0; ni < 4; ++ni) acc[mi][ni] += av[mi] * bv[ni];
    }
    __syncthreads();
  }

  const int col = col0 + tx * 4;
  const int t = col / 192;
  const int rem = col % 192;
  const int h = rem >> 5;
  const int d0 = rem & 31;
  float* dst = (t == 0) ? q : (t == 1) ? k : v;
  const float sc = (t == 0) ? kScale : 1.0f;
  const float4 bvec = make_float4(b1[col], b1[col + 1], b1[col + 2], b1[col + 3]);
#pragma unroll
  for (int mi = 0; mi < 8; ++mi) {
    const int row = row0 + (mi < 4 ? ty * 4 + mi : 64 + ty * 4 + (mi - 4));
    const int w = row / 144;
    const int l = row % 144;
    float4 o;
    o.x = (acc[mi][0] + bvec.x) * sc;
    o.y = (acc[mi][1] + bvec.y) * sc;
    o.z = (acc[mi][2] + bvec.z) * sc;
    o.w = (acc[mi][3] + bvec.w) * sc;
    *(float4*)&dst[(((size_t)(w * 6 + h)) * 144 + l) * 32 + d0] = o;
  }
}

// ---------------------------------------------------------------------------
// Kernel B: fused attention per (window, head). 1024 threads (16 waves/CU).
// S stored transposed: S[j][i]. Bias staged in LDS (3312 distinct values).
// ---------------------------------------------------------------------------
__global__ __launch_bounds__(1024, 1) void attn_kernel(
    const float* __restrict__ q, const float* __restrict__ k,
    const float* __restrict__ v, const float* __restrict__ mask,
    const float* __restrict__ bt, float* __restrict__ ao)
{
  __shared__ __align__(16) float Qs[32][148];   // [d][i]
  __shared__ __align__(16) float Ks[32][148];   // [d][j]
  __shared__ __align__(16) float Vs[144][36];   // [j][d]
  __shared__ __align__(16) float S[144][148];   // [j][i]
  __shared__ __align__(16) float Bs[3312];      // bias values for this (tow,h)
  __shared__ float Sinv[144];

  const int w = blockIdx.x / 6;
  const int h = blockIdx.x % 6;
  const int tid = threadIdx.x;
  const int tow = w % 240;
  const int bth = tow * 6 + h;
  const size_t base = ((size_t)(w * 6 + h)) * 144 * 32;
  const float* mrow = mask + (size_t)w * 20736;

  // --- stage bias: 3312 scattered loads (stride 5760B), once per block ---
  for (int p = tid; p < 3312; p += 1024)
    Bs[p] = bt[(size_t)p * 1440 + bth];

  // --- V load: coalesced, [j][d] layout ---
  for (int f = tid; f < 1152; f += 1024) {
    const int l = f >> 3;
    const int d0 = (f & 7) << 2;
    float4 vv = *(const float4*)&v[base + l * 32 + d0];
    *(float4*)&Vs[l][d0] = vv;
  }
  // --- Q,K transposed loads; lane map keeps LDS stores <=2-way-conflicted
  //     and global reads 64B-line coalesced:
  //     f bits: [3:0]=l_lo, [6:4]=d_quad, [10:7]=l_hi  (bijective over 1152) ---
  for (int f = tid; f < 1152; f += 1024) {
    const int l = (f & 15) | ((f >> 7) << 4);
    const int d0 = ((f >> 4) & 7) << 2;
    float4 qv = *(const float4*)&q[base + l * 32 + d0];
    Qs[d0 + 0][l] = qv.x; Qs[d0 + 1][l] = qv.y;
    Qs[d0 + 2][l] = qv.z; Qs[d0 + 3][l] = qv.w;
    float4 kv = *(const float4*)&k[base + l * 32 + d0];
    Ks[d0 + 0][l] = kv.x; Ks[d0 + 1][l] = kv.y;
    Ks[d0 + 2][l] = kv.z; Ks[d0 + 3][l] = kv.w;
  }
  __syncthreads();

  // --- S phase: 36x36 grid of 4x4 tiles = 1296 tiles, grid-stride ---
  for (int tile = tid; tile < 1296; tile += 1024) {
    const int it = tile % 36;
    const int jt = tile / 36;
    const int i0 = it * 4;
    const int j0 = jt * 4;
    float sacc[4][4];  // [jj][ii]
#pragma unroll
    for (int a = 0; a < 4; ++a)
#pragma unroll
      for (int b = 0; b < 4; ++b) sacc[a][b] = 0.f;
#pragma unroll 4
    for (int d = 0; d < 32; ++d) {
      float4 qv = *(const float4*)&Qs[d][i0];
      float4 kv = *(const float4*)&Ks[d][j0];
      float qa[4] = {qv.x, qv.y, qv.z, qv.w};
      float ka[4] = {kv.x, kv.y, kv.z, kv.w};
#pragma unroll
      for (int jj = 0; jj < 4; ++jj)
#pragma unroll
        for (int ii = 0; ii < 4; ++ii) sacc[jj][ii] += ka[jj] * qa[ii];
    }
    // bias: within a 4-aligned tile (4|12), z/h are constant; pos = C + ii - jj
    // -> only 7 distinct bias values per tile, read from LDS.
    const int zi = i0 / 72, hi = (i0 / 12) % 6, wi0 = i0 % 12;
    const int zj = j0 / 72, hj = (j0 / 12) % 6, wj0 = j0 % 12;
    const int C = 828 * zi + 23 * hi + wi0 + 11 + 1656 * zj + 138 * hj - wj0;
    float bvals[7];
#pragma unroll
    for (int t = 0; t < 7; ++t) bvals[t] = Bs[C - 3 + t];
    float mvv[4][4];  // [ii][jj]
#pragma unroll
    for (int ii = 0; ii < 4; ++ii) {
      float4 mv = *(const float4*)&mrow[(i0 + ii) * 144 + j0];
      mvv[ii][0] = mv.x; mvv[ii][1] = mv.y; mvv[ii][2] = mv.z; mvv[ii][3] = mv.w;
    }
#pragma unroll
    for (int jj = 0; jj < 4; ++jj) {
      float4 sv;
      sv.x = sacc[jj][0] + bvals[3 + 0 - jj] + mvv[0][jj];
      sv.y = sacc[jj][1] + bvals[3 + 1 - jj] + mvv[1][jj];
      sv.z = sacc[jj][2] + bvals[3 + 2 - jj] + mvv[2][jj];
      sv.w = sacc[jj][3] + bvals[3 + 3 - jj] + mvv[3][jj];
      *(float4*)&S[j0 + jj][i0] = sv;
    }
  }
  __syncthreads();

  // --- softmax over j, 4 threads per column i, quad shfl reduce ---
  if (tid < 576) {
    const int i = tid >> 2;
    const int qd = tid & 3;
    const int jb = qd * 36;
    float m = -1e30f;
    for (int j = jb; j < jb + 36; ++j) m = fmaxf(m, S[j][i]);
    m = fmaxf(m, __shfl_xor(m, 1));
    m = fmaxf(m, __shfl_xor(m, 2));
    float s = 0.f;
    for (int j = jb; j < jb + 36; ++j) {
      float e = __expf(S[j][i] - m);
      S[j][i] = e;
      s += e;
    }
    s += __shfl_xor(s, 1);
    s += __shfl_xor(s, 2);
    if (qd == 0) Sinv[i] = 1.0f / s;
  }
  __syncthreads();

  // --- PV: O[i][d] = sum_j P[j][i] * V[j][d]; 72(i-pairs) x 8(d-quads) ---
  if (tid < 576) {
    const int i0 = (tid >> 3) * 2;
    const int d0 = (tid & 7) * 4;
    float oacc[2][4];
#pragma unroll
    for (int a = 0; a < 2; ++a)
#pragma unroll
      for (int b = 0; b < 4; ++b) oacc[a][b] = 0.f;
#pragma unroll 4
    for (int j = 0; j < 144; ++j) {
      float2 pv = *(const float2*)&S[j][i0];
      float4 vv = *(const float4*)&Vs[j][d0];
      float pa[2] = {pv.x, pv.y};
      float va[4] = {vv.x, vv.y, vv.z, vv.w};
#pragma unroll
      for (int ii = 0; ii < 2; ++ii)
#pragma unroll
        for (int dd = 0; dd < 4; ++dd) oacc[ii][dd] += pa[ii] * va[dd];
    }
#pragma unroll
    for (int ii = 0; ii < 2; ++ii) {
      const int i = i0 + ii;
      const float inv = Sinv[i];
      float4 o = make_float4(oacc[ii][0] * inv, oacc[ii][1] * inv,
                             oacc[ii][2] * inv, oacc[ii][3] * inv);
      *(float4*)&ao[((size_t)(w * 144 + i)) * 192 + h * 32 + d0] = o;
    }
  }
}

// ---------------------------------------------------------------------------
// Kernel C: output projection. M=103680, K=192, N=192. Same structure as A.
// ---------------------------------------------------------------------------
__global__ __launch_bounds__(256) void proj_kernel(
    const float* __restrict__ xin, const float* __restrict__ w2,
    const float* __restrict__ b2, float* __restrict__ out)
{
  __shared__ __align__(16) float Xs[64][132];
  __shared__ __align__(16) float Ws[64][68];
  const int mt = blockIdx.x / 3;
  const int nt = blockIdx.x % 3;
  const int row0 = mt * 128;
  const int col0 = nt * 64;
  const int tid = threadIdx.x;
  const int tx = tid & 15;
  const int ty = tid >> 4;

  float acc[8][4];
#pragma unroll
  for (int a = 0; a < 8; ++a)
#pragma unroll
    for (int b = 0; b < 4; ++b) acc[a][b] = 0.f;

  for (int kc = 0; kc < 192; kc += 64) {
#pragma unroll
    for (int rr = 0; rr < 128; rr += 16) {
      const int r = rr + ty;
      float4 xv = *(const float4*)&xin[(size_t)(row0 + r) * 192 + kc + tx * 4];
      Xs[tx * 4 + 0][r] = xv.x; Xs[tx * 4 + 1][r] = xv.y;
      Xs[tx * 4 + 2][r] = xv.z; Xs[tx * 4 + 3][r] = xv.w;
    }
#pragma unroll
    for (int cc = 0; cc < 64; cc += 16) {
      const int c = cc + ty;
      float4 wv = *(const float4*)&w2[(size_t)(col0 + c) * 192 + kc + tx * 4];
      Ws[tx * 4 + 0][c] = wv.x; Ws[tx * 4 + 1][c] = wv.y;
      Ws[tx * 4 + 2][c] = wv.z; Ws[tx * 4 + 3][c] = wv.w;
    }
    __syncthreads();
#pragma unroll 4
    for (int kz = 0; kz < 64; ++kz) {
      float4 a0 = *(const float4*)&Xs[kz][ty * 4];
      float4 a1 = *(const float4*)&Xs[kz][64 + ty * 4];
      float4 bb = *(const float4*)&Ws[kz][tx * 4];
      float av[8] = {a0.x, a0.y, a0.z, a0.w, a1.x, a1.y, a1.z, a1.w};
      float bv[4] = {bb.x, bb.y, bb.z, bb.w};
#pragma unroll
      for (int mi = 0; mi < 8; ++mi)
#pragma unroll
        for (int ni = 0; ni < 4; ++ni) acc[mi][ni] += av[mi] * bv[ni];
    }
    __syncthreads();
  }

  const int col = col0 + tx * 4;
  const float4 bvec = make_float4(b2[col], b2[col + 1], b2[col + 2], b2[col + 3]);
#pragma unroll
  for (int mi = 0; mi < 8; ++mi) {
    const int row = row0 + (mi < 4 ? ty * 4 + mi : 64 + ty * 4 + (mi - 4));
    float4 o = make_float4(acc[mi][0] + bvec.x, acc[mi][1] + bvec.y,
                           acc[mi][2] + bvec.z, acc[mi][3] + bvec.w);
    *(float4*)&out[(size_t)row * 192 + col] = o;
  }
}

// ---------------------------------------------------------------------------
extern "C" void kernel_launch(void* const* d_in, const int* in_sizes, int n_in,
                              void* d_out, int out_size, void* d_ws, size_t ws_size,
                              hipStream_t stream)
{
  const float* x    = (const float*)d_in[0];  // (720,144,192)
  const float* mask = (const float*)d_in[1];  // (720,144,144)
  const float* w1   = (const float*)d_in[2];  // (576,192)
  const float* b1   = (const float*)d_in[3];  // (576,)
  const float* w2   = (const float*)d_in[4];  // (192,192)
  const float* b2   = (const float*)d_in[5];  // (192,)
  const float* bt   = (const float*)d_in[6];  // (3312,240,6)
  float* out = (float*)d_out;

  float* q  = (float*)d_ws;
  float* k  = q + kQKVElems;
  float* v  = k + kQKVElems;
  float* ao = v + kQKVElems;  // [w][l][192]

  qkv_kernel<<<810 * 9, 256, 0, stream>>>(x, w1, b1, q, k, v);
  attn_kernel<<<kNW * 6, 1024, 0, stream>>>(q, k, v, mask, bt, ao);
  proj_kernel<<<810 * 3, 256, 0, stream>>>(ao, w2, b2, out);
}

// Round 3
// 734.450 us; speedup vs baseline: 1.3815x; 1.1201x over previous
//
#include <hip/hip_runtime.h>
#include <cstdint>
#include <cstddef>

// EarthAttention3D (Pangu-Weather): NW=720, L=144, DIM=192, H=6, hd=32
//   A: qkv = x @ w1^T + b1 -> q,k,v [w][h][l][d] (q pre-scaled), split-bf16 MFMA
//   B: per (w,h): S = K.Q^T + bias + mask; softmax over j; O = P^T.V (fp32, XCD-swizzled)
//   C: out = ao @ w2^T + b2, split-bf16 MFMA
// Split-bf16: a = hi + lo (both bf16); a*b ~= hi*hi + hi*lo + lo*hi (rel err ~2^-17).
// MFMA 16x16x32 bf16 layouts (m89-verified): A/B row-major, row = lane&15,
// k = (lane>>4)*8 + j (8 contiguous bf16 = 1 ds_read_b128). C/D: col = lane&15,
// row = (lane>>4)*4 + reg.

using short8 = __attribute__((ext_vector_type(8))) short;
using f32x4  = __attribute__((ext_vector_type(4))) float;

constexpr int kNW = 720;
constexpr float kScale = 0.17677669529663687f;  // 32^-0.5
constexpr size_t kQKVElems = (size_t)kNW * 6 * 144 * 32;  // 19,906,560

__device__ __forceinline__ ushort bf16_rne(float f) {
  uint u = __builtin_bit_cast(uint, f);
  return (ushort)((u + 0x7FFFu + ((u >> 16) & 1u)) >> 16);
}
__device__ __forceinline__ float bf16_to_f(ushort h) {
  uint u = ((uint)h) << 16;
  return __builtin_bit_cast(float, u);
}

// ---------------------------------------------------------------------------
// Split-bf16 MFMA GEMM: out[M,N] = X[M,192] @ W[N,192]^T + bias.
// Block: 256 thr (4 waves), BM=64, BN=192, K-chunks of 64.
// Wave grid 1x4 (N): wave computes 64x48 = 4(m) x 3(n) 16x16 tiles.
// LDS rows padded to 72 bf16 (144B): b128 reads rotate 4 banks/row -> <=2-way.
// IS_QKV: N=576 in 3 block-cols, scatter epilogue to q/k/v (q scaled).
// else:   N=192 single col, plain epilogue to out0.
// ---------------------------------------------------------------------------
template <bool IS_QKV>
__global__ __launch_bounds__(256) void gemm_kernel(
    const float* __restrict__ X, const float* __restrict__ W,
    const float* __restrict__ bias, float* __restrict__ out0,
    float* __restrict__ out1, float* __restrict__ out2)
{
  __shared__ ushort Ah[64][72], Al[64][72];
  __shared__ ushort Bh[192][72], Bl[192][72];

  const int bid = blockIdx.x;
  const int mtile = IS_QKV ? bid / 3 : bid;
  const int col0  = IS_QKV ? (bid % 3) * 192 : 0;
  const int row0 = mtile * 64;
  const int tid = threadIdx.x;
  const int s  = tid & 15;   // 16B k-slot (4 floats)
  const int r0 = tid >> 4;   // 0..15
  const int wv = tid >> 6;   // wave 0..3
  const int lane = tid & 63;
  const int rr = lane & 15;  // frag row/col
  const int kg = lane >> 4;  // k-group 0..3
  const int nbase = wv * 48;

  f32x4 acc[4][3];
#pragma unroll
  for (int a = 0; a < 4; ++a)
#pragma unroll
    for (int b = 0; b < 3; ++b) acc[a][b] = (f32x4){0.f, 0.f, 0.f, 0.f};

  for (int kc = 0; kc < 192; kc += 64) {
    // stage A: 64 rows x 64 k, fp32 -> (hi,lo) bf16
#pragma unroll
    for (int it = 0; it < 4; ++it) {
      const int r = r0 + it * 16;
      float4 xv = *(const float4*)&X[(size_t)(row0 + r) * 192 + kc + s * 4];
      ushort4 hv, lv;
      hv.x = bf16_rne(xv.x); lv.x = bf16_rne(xv.x - bf16_to_f(hv.x));
      hv.y = bf16_rne(xv.y); lv.y = bf16_rne(xv.y - bf16_to_f(hv.y));
      hv.z = bf16_rne(xv.z); lv.z = bf16_rne(xv.z - bf16_to_f(hv.z));
      hv.w = bf16_rne(xv.w); lv.w = bf16_rne(xv.w - bf16_to_f(hv.w));
      *(ushort4*)&Ah[r][s * 4] = hv;
      *(ushort4*)&Al[r][s * 4] = lv;
    }
    // stage B: 192 rows (n) x 64 k
#pragma unroll
    for (int it = 0; it < 12; ++it) {
      const int n = r0 + it * 16;
      float4 wvv = *(const float4*)&W[(size_t)(col0 + n) * 192 + kc + s * 4];
      ushort4 hv, lv;
      hv.x = bf16_rne(wvv.x); lv.x = bf16_rne(wvv.x - bf16_to_f(hv.x));
      hv.y = bf16_rne(wvv.y); lv.y = bf16_rne(wvv.y - bf16_to_f(hv.y));
      hv.z = bf16_rne(wvv.z); lv.z = bf16_rne(wvv.z - bf16_to_f(hv.z));
      hv.w = bf16_rne(wvv.w); lv.w = bf16_rne(wvv.w - bf16_to_f(hv.w));
      *(ushort4*)&Bh[n][s * 4] = hv;
      *(ushort4*)&Bl[n][s * 4] = lv;
    }
    __syncthreads();

#pragma unroll
    for (int ks = 0; ks < 2; ++ks) {
      const int kb = ks * 32 + kg * 8;  // element offset within 64-k chunk
      short8 ah[4], al4[4], bh[3], bl[3];
#pragma unroll
      for (int mt = 0; mt < 4; ++mt) {
        ah[mt]  = *(const short8*)&Ah[mt * 16 + rr][kb];
        al4[mt] = *(const short8*)&Al[mt * 16 + rr][kb];
      }
#pragma unroll
      for (int nt = 0; nt < 3; ++nt) {
        bh[nt] = *(const short8*)&Bh[nbase + nt * 16 + rr][kb];
        bl[nt] = *(const short8*)&Bl[nbase + nt * 16 + rr][kb];
      }
#pragma unroll
      for (int mt = 0; mt < 4; ++mt)
#pragma unroll
        for (int nt = 0; nt < 3; ++nt) {
          acc[mt][nt] = __builtin_amdgcn_mfma_f32_16x16x32_bf16(ah[mt],  bh[nt], acc[mt][nt], 0, 0, 0);
          acc[mt][nt] = __builtin_amdgcn_mfma_f32_16x16x32_bf16(ah[mt],  bl[nt], acc[mt][nt], 0, 0, 0);
          acc[mt][nt] = __builtin_amdgcn_mfma_f32_16x16x32_bf16(al4[mt], bh[nt], acc[mt][nt], 0, 0, 0);
        }
    }
    __syncthreads();
  }

  if (IS_QKV) {
    const int t = col0 / 192;  // uniform per block
    float* dst = (t == 0) ? out0 : (t == 1) ? out1 : out2;
    const float sc = (t == 0) ? kScale : 1.0f;
#pragma unroll
    for (int nt = 0; nt < 3; ++nt) {
      const int c0 = nbase + nt * 16;       // 0..176 (16-aligned)
      const int h  = c0 >> 5;               // uniform per tile
      const int d0 = (c0 & 31) + rr;
      const float bcol = bias[col0 + c0 + rr];
#pragma unroll
      for (int mt = 0; mt < 4; ++mt)
#pragma unroll
        for (int reg = 0; reg < 4; ++reg) {
          const int grow = row0 + mt * 16 + kg * 4 + reg;
          const int w = grow / 144;
          const int l = grow % 144;
          dst[(((size_t)(w * 6 + h)) * 144 + l) * 32 + d0] =
              (acc[mt][nt][reg] + bcol) * sc;
        }
    }
  } else {
#pragma unroll
    for (int nt = 0; nt < 3; ++nt) {
      const int c = nbase + nt * 16 + rr;
      const float bcol = bias[c];
#pragma unroll
      for (int mt = 0; mt < 4; ++mt)
#pragma unroll
        for (int reg = 0; reg < 4; ++reg) {
          const int grow = row0 + mt * 16 + kg * 4 + reg;
          out0[(size_t)grow * 192 + c] = acc[mt][nt][reg] + bcol;
        }
    }
  }
}

// ---------------------------------------------------------------------------
// Kernel B: fused attention per (window, head). 1024 threads.
// XCD-bijective chunked remap (4320 = 8*540): all 6 heads of a window on one
// XCD -> mask read hits that XCD's L2 instead of re-fetching from HBM.
// ---------------------------------------------------------------------------
__global__ __launch_bounds__(1024, 1) void attn_kernel(
    const float* __restrict__ q, const float* __restrict__ k,
    const float* __restrict__ v, const float* __restrict__ mask,
    const float* __restrict__ bt, float* __restrict__ ao)
{
  __shared__ __align__(16) float Qs[32][148];   // [d][i]
  __shared__ __align__(16) float Ks[32][148];   // [d][j]
  __shared__ __align__(16) float Vs[144][36];   // [j][d]
  __shared__ __align__(16) float S[144][148];   // [j][i]
  __shared__ __align__(16) float Bs[3312];
  __shared__ float Sinv[144];

  const int bid = blockIdx.x;
  const int wid = (bid & 7) * 540 + (bid >> 3);  // bijective: 4320 = 8*540
  const int w = wid / 6;
  const int h = wid % 6;
  const int tid = threadIdx.x;
  const int tow = w % 240;
  const int bth = tow * 6 + h;
  const size_t base = ((size_t)(w * 6 + h)) * 144 * 32;
  const float* mrow = mask + (size_t)w * 20736;

  for (int p = tid; p < 3312; p += 1024)
    Bs[p] = bt[(size_t)p * 1440 + bth];

  for (int f = tid; f < 1152; f += 1024) {
    const int l = f >> 3;
    const int d0 = (f & 7) << 2;
    float4 vvv = *(const float4*)&v[base + l * 32 + d0];
    *(float4*)&Vs[l][d0] = vvv;
  }
  for (int f = tid; f < 1152; f += 1024) {
    const int l = (f & 15) | ((f >> 7) << 4);
    const int d0 = ((f >> 4) & 7) << 2;
    float4 qv = *(const float4*)&q[base + l * 32 + d0];
    Qs[d0 + 0][l] = qv.x; Qs[d0 + 1][l] = qv.y;
    Qs[d0 + 2][l] = qv.z; Qs[d0 + 3][l] = qv.w;
    float4 kv = *(const float4*)&k[base + l * 32 + d0];
    Ks[d0 + 0][l] = kv.x; Ks[d0 + 1][l] = kv.y;
    Ks[d0 + 2][l] = kv.z; Ks[d0 + 3][l] = kv.w;
  }
  __syncthreads();

  for (int tile = tid; tile < 1296; tile += 1024) {
    const int it = tile % 36;
    const int jt = tile / 36;
    const int i0 = it * 4;
    const int j0 = jt * 4;
    float sacc[4][4];  // [jj][ii]
#pragma unroll
    for (int a = 0; a < 4; ++a)
#pragma unroll
      for (int b = 0; b < 4; ++b) sacc[a][b] = 0.f;
#pragma unroll 4
    for (int d = 0; d < 32; ++d) {
      float4 qv = *(const float4*)&Qs[d][i0];
      float4 kv = *(const float4*)&Ks[d][j0];
      float qa[4] = {qv.x, qv.y, qv.z, qv.w};
      float ka[4] = {kv.x, kv.y, kv.z, kv.w};
#pragma unroll
      for (int jj = 0; jj < 4; ++jj)
#pragma unroll
        for (int ii = 0; ii < 4; ++ii) sacc[jj][ii] += ka[jj] * qa[ii];
    }
    const int zi = i0 / 72, hi = (i0 / 12) % 6, wi0 = i0 % 12;
    const int zj = j0 / 72, hj = (j0 / 12) % 6, wj0 = j0 % 12;
    const int C = 828 * zi + 23 * hi + wi0 + 11 + 1656 * zj + 138 * hj - wj0;
    float bvals[7];
#pragma unroll
    for (int t = 0; t < 7; ++t) bvals[t] = Bs[C - 3 + t];
    float mvv[4][4];  // [ii][jj]
#pragma unroll
    for (int ii = 0; ii < 4; ++ii) {
      float4 mv = *(const float4*)&mrow[(i0 + ii) * 144 + j0];
      mvv[ii][0] = mv.x; mvv[ii][1] = mv.y; mvv[ii][2] = mv.z; mvv[ii][3] = mv.w;
    }
#pragma unroll
    for (int jj = 0; jj < 4; ++jj) {
      float4 sv;
      sv.x = sacc[jj][0] + bvals[3 + 0 - jj] + mvv[0][jj];
      sv.y = sacc[jj][1] + bvals[3 + 1 - jj] + mvv[1][jj];
      sv.z = sacc[jj][2] + bvals[3 + 2 - jj] + mvv[2][jj];
      sv.w = sacc[jj][3] + bvals[3 + 3 - jj] + mvv[3][jj];
      *(float4*)&S[j0 + jj][i0] = sv;
    }
  }
  __syncthreads();

  if (tid < 576) {
    const int i = tid >> 2;
    const int qd = tid & 3;
    const int jb = qd * 36;
    float m = -1e30f;
    for (int j = jb; j < jb + 36; ++j) m = fmaxf(m, S[j][i]);
    m = fmaxf(m, __shfl_xor(m, 1));
    m = fmaxf(m, __shfl_xor(m, 2));
    float sum = 0.f;
    for (int j = jb; j < jb + 36; ++j) {
      float e = __expf(S[j][i] - m);
      S[j][i] = e;
      sum += e;
    }
    sum += __shfl_xor(sum, 1);
    sum += __shfl_xor(sum, 2);
    if (qd == 0) Sinv[i] = 1.0f / sum;
  }
  __syncthreads();

  if (tid < 576) {
    const int i0 = (tid >> 3) * 2;
    const int d0 = (tid & 7) * 4;
    float oacc[2][4];
#pragma unroll
    for (int a = 0; a < 2; ++a)
#pragma unroll
      for (int b = 0; b < 4; ++b) oacc[a][b] = 0.f;
#pragma unroll 4
    for (int j = 0; j < 144; ++j) {
      float2 pv = *(const float2*)&S[j][i0];
      float4 vvv = *(const float4*)&Vs[j][d0];
      float pa[2] = {pv.x, pv.y};
      float va[4] = {vvv.x, vvv.y, vvv.z, vvv.w};
#pragma unroll
      for (int ii = 0; ii < 2; ++ii)
#pragma unroll
        for (int dd = 0; dd < 4; ++dd) oacc[ii][dd] += pa[ii] * va[dd];
    }
#pragma unroll
    for (int ii = 0; ii < 2; ++ii) {
      const int i = i0 + ii;
      const float inv = Sinv[i];
      float4 o = make_float4(oacc[ii][0] * inv, oacc[ii][1] * inv,
                             oacc[ii][2] * inv, oacc[ii][3] * inv);
      *(float4*)&ao[((size_t)(w * 144 + i)) * 192 + h * 32 + d0] = o;
    }
  }
}

// ---------------------------------------------------------------------------
extern "C" void kernel_launch(void* const* d_in, const int* in_sizes, int n_in,
                              void* d_out, int out_size, void* d_ws, size_t ws_size,
                              hipStream_t stream)
{
  const float* x    = (const float*)d_in[0];  // (720,144,192)
  const float* mask = (const float*)d_in[1];  // (720,144,144)
  const float* w1   = (const float*)d_in[2];  // (576,192)
  const float* b1   = (const float*)d_in[3];  // (576,)
  const float* w2   = (const float*)d_in[4];  // (192,192)
  const float* b2   = (const float*)d_in[5];  // (192,)
  const float* bt   = (const float*)d_in[6];  // (3312,240,6)
  float* out = (float*)d_out;

  float* q  = (float*)d_ws;
  float* k  = q + kQKVElems;
  float* v  = k + kQKVElems;
  float* ao = v + kQKVElems;  // [w][l][192]

  gemm_kernel<true><<<1620 * 3, 256, 0, stream>>>(x, w1, b1, q, k, v);
  attn_kernel<<<kNW * 6, 1024, 0, stream>>>(q, k, v, mask, bt, ao);
  gemm_kernel<false><<<1620, 256, 0, stream>>>(ao, w2, b2, out, nullptr, nullptr);
}

// Round 4
// 503.637 us; speedup vs baseline: 2.0146x; 1.4583x over previous
//
#include <hip/hip_runtime.h>
#include <cstdint>
#include <cstddef>

// EarthAttention3D (Pangu-Weather): NW=720, L=144, DIM=192, H=6, hd=32
// All matmuls on MFMA 16x16x32 bf16 with split-bf16 (a = hi+lo; a*b ~= hh+hl+lh,
// rel err ~2^-17 ~ fp32-grade).
// MFMA layouts (validated rounds 2-3 on this problem): A/B row-major [m|n][k],
// row = lane&15, k = (lane>>4)*8 + t (8 contiguous bf16 = ds_read_b128).
// C/D: col(n) = lane&15, row(m) = (lane>>4)*4 + reg.
//
// Pipeline: prep(w1) -> qkv(GEMM, writes q/k/v as hi/lo ushort planes)
//        -> attn (MFMA QK^T -> bias/mask -> softmax -> pack P hi/lo -> MFMA PV)
//        -> prep(w2, into dead q-region) -> proj(GEMM, fp32 out).
// pos(i,j) = [828 z_i + 23 h_i + w_i + 11] + [1656 z_j + 138 h_j - w_j],
// i=(z*6+h)*12+w; bias elem = bt[pos*1440 + (w%240)*6 + head].

using short8 = __attribute__((ext_vector_type(8))) short;
using f32x4  = __attribute__((ext_vector_type(4))) float;

constexpr int kNW = 720;
constexpr float kScale = 0.17677669529663687f;  // 32^-0.5
constexpr size_t kQKVElems = (size_t)kNW * 6 * 144 * 32;  // 19,906,560

__device__ __forceinline__ ushort bf16_rne(float f) {
  uint u = __builtin_bit_cast(uint, f);
  return (ushort)((u + 0x7FFFu + ((u >> 16) & 1u)) >> 16);
}
__device__ __forceinline__ float bf16_to_f(ushort h) {
  uint u = ((uint)h) << 16;
  return __builtin_bit_cast(float, u);
}

// ---------------------------------------------------------------------------
// prep: fp32 -> (hi,lo) bf16 planes. Exact grid (n % 256 == 0 in our uses).
// ---------------------------------------------------------------------------
__global__ __launch_bounds__(256) void prep_kernel(
    const float* __restrict__ src, ushort* __restrict__ dh,
    ushort* __restrict__ dl, int n)
{
  const int i = blockIdx.x * 256 + threadIdx.x;
  if (i < n) {
    const float f = src[i];
    const ushort h = bf16_rne(f);
    dh[i] = h;
    dl[i] = bf16_rne(f - bf16_to_f(h));
  }
}

// ---------------------------------------------------------------------------
// GEMM: out[M,N] = X[M,192] @ W[N,192]^T + bias. BM=64, BN=192, BK=32.
// 256 thr (4 waves, 1x4 N-grid): wave computes 4(m) x 3(n) 16x16 tiles.
// LDS 41 KB -> 3 blocks/CU (12 waves). B pre-converted (prep), A converted here.
// IS_QKV: 3 n-col blocks -> scatter ushort hi/lo to q/k/v planes (q scaled).
// else:   fp32 epilogue to fout.
// ---------------------------------------------------------------------------
template <bool IS_QKV>
__global__ __launch_bounds__(256) void gemm_kernel(
    const float* __restrict__ X, const ushort* __restrict__ Wh,
    const ushort* __restrict__ Wl, const float* __restrict__ bias,
    ushort* __restrict__ o0, ushort* __restrict__ o1, ushort* __restrict__ o2,
    ushort* __restrict__ o3, ushort* __restrict__ o4, ushort* __restrict__ o5,
    float* __restrict__ fout)
{
  __shared__ ushort Ah[64][40], Al[64][40];    // rows 80 B -> <=2-way b128 reads
  __shared__ ushort Bh[192][40], Bl[192][40];

  const int bid = blockIdx.x;
  const int mtile = IS_QKV ? bid / 3 : bid;
  const int col0  = IS_QKV ? (bid % 3) * 192 : 0;
  const int row0 = mtile * 64;
  const int tid = threadIdx.x;
  const int wv = tid >> 6;
  const int lane = tid & 63;
  const int rr = lane & 15;
  const int kg = lane >> 4;
  const int nbase = wv * 48;

  f32x4 acc[4][3];
#pragma unroll
  for (int a = 0; a < 4; ++a)
#pragma unroll
    for (int b = 0; b < 3; ++b) acc[a][b] = (f32x4){0.f, 0.f, 0.f, 0.f};

  for (int kc = 0; kc < 192; kc += 32) {
    // A: 64 rows x 32 k fp32 -> hi/lo (512 float4-slots, 2/thread)
#pragma unroll
    for (int u = 0; u < 2; ++u) {
      const int sl = tid * 2 + u;
      const int r = sl >> 3, s = sl & 7;
      float4 xv = *(const float4*)&X[(size_t)(row0 + r) * 192 + kc + s * 4];
      ushort4 hv, lv;
      hv.x = bf16_rne(xv.x); lv.x = bf16_rne(xv.x - bf16_to_f(hv.x));
      hv.y = bf16_rne(xv.y); lv.y = bf16_rne(xv.y - bf16_to_f(hv.y));
      hv.z = bf16_rne(xv.z); lv.z = bf16_rne(xv.z - bf16_to_f(hv.z));
      hv.w = bf16_rne(xv.w); lv.w = bf16_rne(xv.w - bf16_to_f(hv.w));
      *(ushort4*)&Ah[r][s * 4] = hv;
      *(ushort4*)&Al[r][s * 4] = lv;
    }
    // B: 192 rows x 32 k, pre-converted ushort (1536 8B-slots, 6/thread)
#pragma unroll
    for (int u = 0; u < 6; ++u) {
      const int sl = tid + u * 256;
      const int n = sl >> 3, s = sl & 7;
      const size_t g = (size_t)(col0 + n) * 192 + kc + s * 4;
      *(uint2*)&Bh[n][s * 4] = *(const uint2*)&Wh[g];
      *(uint2*)&Bl[n][s * 4] = *(const uint2*)&Wl[g];
    }
    __syncthreads();

    short8 ah[4], al_[4], bh[3], bl[3];
#pragma unroll
    for (int mt = 0; mt < 4; ++mt) {
      ah[mt]  = *(const short8*)&Ah[mt * 16 + rr][kg * 8];
      al_[mt] = *(const short8*)&Al[mt * 16 + rr][kg * 8];
    }
#pragma unroll
    for (int nt = 0; nt < 3; ++nt) {
      bh[nt] = *(const short8*)&Bh[nbase + nt * 16 + rr][kg * 8];
      bl[nt] = *(const short8*)&Bl[nbase + nt * 16 + rr][kg * 8];
    }
#pragma unroll
    for (int mt = 0; mt < 4; ++mt)
#pragma unroll
      for (int nt = 0; nt < 3; ++nt) {
        acc[mt][nt] = __builtin_amdgcn_mfma_f32_16x16x32_bf16(ah[mt],  bh[nt], acc[mt][nt], 0, 0, 0);
        acc[mt][nt] = __builtin_amdgcn_mfma_f32_16x16x32_bf16(ah[mt],  bl[nt], acc[mt][nt], 0, 0, 0);
        acc[mt][nt] = __builtin_amdgcn_mfma_f32_16x16x32_bf16(al_[mt], bh[nt], acc[mt][nt], 0, 0, 0);
      }
    __syncthreads();
  }

  if (IS_QKV) {
    const int t = col0 / 192;  // 0=q 1=k 2=v (uniform per block)
    ushort* dh = (t == 0) ? o0 : (t == 1) ? o2 : o4;
    ushort* dl = (t == 0) ? o1 : (t == 1) ? o3 : o5;
    const float sc = (t == 0) ? kScale : 1.0f;
#pragma unroll
    for (int nt = 0; nt < 3; ++nt) {
      const int c0 = nbase + nt * 16;
      const int hh = c0 >> 5;             // head, uniform per tile
      const int d0 = (c0 & 31) + rr;
      const float bcol = bias[col0 + c0 + rr];
#pragma unroll
      for (int mt = 0; mt < 4; ++mt)
#pragma unroll
        for (int reg = 0; reg < 4; ++reg) {
          const int grow = row0 + mt * 16 + kg * 4 + reg;
          const int w = grow / 144;
          const int l = grow % 144;
          const float vv = (acc[mt][nt][reg] + bcol) * sc;
          const ushort hv = bf16_rne(vv);
          const size_t idx = (((size_t)(w * 6 + hh)) * 144 + l) * 32 + d0;
          dh[idx] = hv;
          dl[idx] = bf16_rne(vv - bf16_to_f(hv));
        }
    }
  } else {
#pragma unroll
    for (int nt = 0; nt < 3; ++nt) {
      const int c = nbase + nt * 16 + rr;
      const float bcol = bias[c];
#pragma unroll
      for (int mt = 0; mt < 4; ++mt)
#pragma unroll
        for (int reg = 0; reg < 4; ++reg) {
          const int grow = row0 + mt * 16 + kg * 4 + reg;
          fout[(size_t)grow * 192 + c] = acc[mt][nt][reg] + bcol;
        }
    }
  }
}

// ---------------------------------------------------------------------------
// attn: one block per (window, head), 1024 thr (16 waves), XCD-bijective remap.
// Phase 1: S tiles (9x9) via 3x MFMA; bias+mask in regs; S[i][j] fp32 -> LDS.
// Phase 2: softmax (4 lanes/row) + in-place pack of P as hi/lo bf16 (j padded
//          to 160 with zeros).  V^T staged hi/lo over the dead K LDS region
//          (loads issued at kernel start, T14).
// Phase 3: O = P.V via 3x MFMA (K-steps j=5x32), fp32 out to ao.
// LDS: QK 46.1 KB + SP 94.5 KB + Bs 13.2 KB = 153.8 KB (1 block/CU, 16 waves).
// ---------------------------------------------------------------------------
__global__ __launch_bounds__(1024, 1) void attn_kernel(
    const ushort* __restrict__ qh, const ushort* __restrict__ ql,
    const ushort* __restrict__ kh, const ushort* __restrict__ kl,
    const ushort* __restrict__ vh, const ushort* __restrict__ vl,
    const float* __restrict__ mask, const float* __restrict__ bt,
    float* __restrict__ ao)
{
  __shared__ ushort QK[4][144][40];   // Qh,Ql,Kh,Kl; rows 80 B
  __shared__ float SP[144][164];      // S fp32; then P: hi@ushort[0,160), lo@[168,328)
  __shared__ float Bs[3312];

  const int bid = blockIdx.x;
  const int wid = (bid & 7) * 540 + (bid >> 3);  // bijective: 4320 = 8*540
  const int w = wid / 6;
  const int h = wid % 6;
  const int tid = threadIdx.x;
  const int wave = tid >> 6;
  const int lane = tid & 63;
  const int rr = lane & 15;
  const int kg = lane >> 4;
  const int bth = (w % 240) * 6 + h;
  const size_t base = ((size_t)(w * 6 + h)) * 4608;
  const float* mrow = mask + (size_t)w * 20736;

  // T14: issue V loads now; LDS-write after phase 1 (region is busy until then)
  const uint2* vh4 = (const uint2*)(vh + base);  // 1152 uint2
  const uint2* vl4 = (const uint2*)(vl + base);
  uint2 rvh0 = vh4[tid], rvl0 = vl4[tid];
  uint2 rvh1, rvl1;
  if (tid < 128) { rvh1 = vh4[1024 + tid]; rvl1 = vl4[1024 + tid]; }

  // bias gather (3312 scattered, stride 5760 B)
  for (int p = tid; p < 3312; p += 1024)
    Bs[p] = bt[(size_t)p * 1440 + bth];

  // Q/K fragment staging: [l][d] rows, direct copy (pre-split by qkv kernel)
  const uint2* qh4 = (const uint2*)(qh + base);
  const uint2* ql4 = (const uint2*)(ql + base);
  const uint2* kh4 = (const uint2*)(kh + base);
  const uint2* kl4 = (const uint2*)(kl + base);
  for (int f = tid; f < 1152; f += 1024) {
    const int l = f >> 3, d0 = (f & 7) * 4;
    *(uint2*)&QK[0][l][d0] = qh4[f];
    *(uint2*)&QK[1][l][d0] = ql4[f];
    *(uint2*)&QK[2][l][d0] = kh4[f];
    *(uint2*)&QK[3][l][d0] = kl4[f];
  }
  __syncthreads();

  // --- Phase 1: S = Q.K^T + bias + mask ---
  for (int t5 = wave; t5 < 81; t5 += 16) {
    const int it = t5 / 9, jt = t5 % 9;
    const int i0 = it * 16, j0 = jt * 16;
    const short8 ah = *(const short8*)&QK[0][i0 + rr][kg * 8];
    const short8 al = *(const short8*)&QK[1][i0 + rr][kg * 8];
    const short8 bh = *(const short8*)&QK[2][j0 + rr][kg * 8];
    const short8 bl = *(const short8*)&QK[3][j0 + rr][kg * 8];
    f32x4 c = (f32x4){0.f, 0.f, 0.f, 0.f};
    c = __builtin_amdgcn_mfma_f32_16x16x32_bf16(ah, bh, c, 0, 0, 0);
    c = __builtin_amdgcn_mfma_f32_16x16x32_bf16(ah, bl, c, 0, 0, 0);
    c = __builtin_amdgcn_mfma_f32_16x16x32_bf16(al, bh, c, 0, 0, 0);
    const int j = j0 + rr;
    const int pj = 1656 * (j / 72) + 138 * ((j / 12) % 6) - (j % 12);
    const int ib = i0 + kg * 4;
#pragma unroll
    for (int reg = 0; reg < 4; ++reg) {
      const int i = ib + reg;
      const int pi = 828 * (i / 72) + 23 * ((i / 12) % 6) + (i % 12) + 11;
      SP[i][j] = c[reg] + Bs[pi + pj] + mrow[i * 144 + j];
    }
  }
  __syncthreads();

  // --- V^T staging over dead K region (rows padded to 168 ushorts) ---
  ushort* Vth = &QK[2][0][0];  // [32][168], 5376 <= 5760 avail
  ushort* Vtl = &QK[3][0][0];
  {
    const int l = tid >> 3, d0 = (tid & 7) * 4;
    Vth[(d0 + 0) * 168 + l] = (ushort)(rvh0.x & 0xffff);
    Vth[(d0 + 1) * 168 + l] = (ushort)(rvh0.x >> 16);
    Vth[(d0 + 2) * 168 + l] = (ushort)(rvh0.y & 0xffff);
    Vth[(d0 + 3) * 168 + l] = (ushort)(rvh0.y >> 16);
    Vtl[(d0 + 0) * 168 + l] = (ushort)(rvl0.x & 0xffff);
    Vtl[(d0 + 1) * 168 + l] = (ushort)(rvl0.x >> 16);
    Vtl[(d0 + 2) * 168 + l] = (ushort)(rvl0.y & 0xffff);
    Vtl[(d0 + 3) * 168 + l] = (ushort)(rvl0.y >> 16);
  }
  if (tid < 128) {
    const int f = 1024 + tid;
    const int l = f >> 3, d0 = (f & 7) * 4;
    Vth[(d0 + 0) * 168 + l] = (ushort)(rvh1.x & 0xffff);
    Vth[(d0 + 1) * 168 + l] = (ushort)(rvh1.x >> 16);
    Vth[(d0 + 2) * 168 + l] = (ushort)(rvh1.y & 0xffff);
    Vth[(d0 + 3) * 168 + l] = (ushort)(rvh1.y >> 16);
    Vtl[(d0 + 0) * 168 + l] = (ushort)(rvl1.x & 0xffff);
    Vtl[(d0 + 1) * 168 + l] = (ushort)(rvl1.x >> 16);
    Vtl[(d0 + 2) * 168 + l] = (ushort)(rvl1.y & 0xffff);
    Vtl[(d0 + 3) * 168 + l] = (ushort)(rvl1.y >> 16);
  }
  // zero-pad j in [144,160) for the 5th K-step
  if (tid < 512) {
    Vth[(tid >> 4) * 168 + 144 + (tid & 15)] = 0;
  } else {
    Vtl[((tid - 512) >> 4) * 168 + 144 + (tid & 15)] = 0;
  }

  // --- Phase 2: softmax over j (4 lanes/row) + in-place hi/lo pack ---
  if (tid < 576) {
    const int i = tid >> 2, qd = tid & 3, jb = qd * 36;
    float e[36];
    float m = -1e30f;
#pragma unroll
    for (int t = 0; t < 36; ++t) { e[t] = SP[i][jb + t]; m = fmaxf(m, e[t]); }
    m = fmaxf(m, __shfl_xor(m, 1));
    m = fmaxf(m, __shfl_xor(m, 2));
    float s = 0.f;
#pragma unroll
    for (int t = 0; t < 36; ++t) { e[t] = __expf(e[t] - m); s += e[t]; }
    s += __shfl_xor(s, 1);
    s += __shfl_xor(s, 2);
    const float inv = 1.0f / s;
    // wave-lockstep: all reads above retire before any write below (same wave)
    ushort* prow = (ushort*)&SP[i][0];
    uint* ph32 = (uint*)prow;          // hi plane, ushort idx j in [0,160)
    uint* pl32 = (uint*)(prow + 168);  // lo plane, 16B-aligned (byte 336)
#pragma unroll
    for (int t = 0; t < 18; ++t) {
      const float p0 = e[2 * t] * inv, p1 = e[2 * t + 1] * inv;
      const ushort h0 = bf16_rne(p0), h1 = bf16_rne(p1);
      const ushort l0 = bf16_rne(p0 - bf16_to_f(h0));
      const ushort l1 = bf16_rne(p1 - bf16_to_f(h1));
      ph32[18 * qd + t] = (uint)h0 | ((uint)h1 << 16);
      pl32[18 * qd + t] = (uint)l0 | ((uint)l1 << 16);
    }
    if (qd == 3) {
#pragma unroll
      for (int t = 0; t < 8; ++t) { ph32[72 + t] = 0; pl32[72 + t] = 0; }
    }
  }
  __syncthreads();

  // --- Phase 3: O[i][d] = P.V, K-steps over j (5 x 32) ---
  for (int t5 = wave; t5 < 18; t5 += 16) {
    const int it = t5 >> 1, dt = t5 & 1;
    const int i0 = it * 16;
    const ushort* prow = (const ushort*)&SP[i0 + rr][0];
    const ushort* vhrow = Vth + (dt * 16 + rr) * 168;
    const ushort* vlrow = Vtl + (dt * 16 + rr) * 168;
    f32x4 o = (f32x4){0.f, 0.f, 0.f, 0.f};
#pragma unroll
    for (int ks = 0; ks < 5; ++ks) {
      const int kb = ks * 32 + kg * 8;
      const short8 pa = *(const short8*)&prow[kb];
      const short8 pb = *(const short8*)&prow[168 + kb];
      const short8 va = *(const short8*)&vhrow[kb];
      const short8 vb = *(const short8*)&vlrow[kb];
      o = __builtin_amdgcn_mfma_f32_16x16x32_bf16(pa, va, o, 0, 0, 0);
      o = __builtin_amdgcn_mfma_f32_16x16x32_bf16(pa, vb, o, 0, 0, 0);
      o = __builtin_amdgcn_mfma_f32_16x16x32_bf16(pb, va, o, 0, 0, 0);
    }
    const int d = dt * 16 + rr;
#pragma unroll
    for (int reg = 0; reg < 4; ++reg) {
      const int i = i0 + kg * 4 + reg;
      ao[((size_t)(w * 144 + i)) * 192 + h * 32 + d] = o[reg];
    }
  }
}

// ---------------------------------------------------------------------------
extern "C" void kernel_launch(void* const* d_in, const int* in_sizes, int n_in,
                              void* d_out, int out_size, void* d_ws, size_t ws_size,
                              hipStream_t stream)
{
  const float* x    = (const float*)d_in[0];  // (720,144,192)
  const float* mask = (const float*)d_in[1];  // (720,144,144)
  const float* w1   = (const float*)d_in[2];  // (576,192)
  const float* b1   = (const float*)d_in[3];  // (576,)
  const float* w2   = (const float*)d_in[4];  // (192,192)
  const float* b2   = (const float*)d_in[5];  // (192,)
  const float* bt   = (const float*)d_in[6];  // (3312,240,6)
  float* out = (float*)d_out;

  // ws layout (total = 318,504,960 B, identical to rounds 1-3):
  ushort* qh = (ushort*)d_ws;
  ushort* ql = qh + kQKVElems;
  ushort* kh = ql + kQKVElems;
  ushort* kl = kh + kQKVElems;
  ushort* vh = kl + kQKVElems;
  ushort* vl = vh + kQKVElems;
  float*  ao = (float*)(vl + kQKVElems);      // 19,906,560 floats
  // w1 planes live inside ao (dead until attn writes it; qkv reads them first)
  ushort* w1h = (ushort*)ao;
  ushort* w1l = w1h + 110592;
  // w2 planes live inside qh (dead after attn reads it; prep2 runs post-attn)
  ushort* w2h = qh;
  ushort* w2l = w2h + 36864;

  prep_kernel<<<432, 256, 0, stream>>>(w1, w1h, w1l, 110592);
  gemm_kernel<true><<<1620 * 3, 256, 0, stream>>>(
      x, w1h, w1l, b1, qh, ql, kh, kl, vh, vl, nullptr);
  attn_kernel<<<4320, 1024, 0, stream>>>(qh, ql, kh, kl, vh, vl, mask, bt, ao);
  prep_kernel<<<144, 256, 0, stream>>>(w2, w2h, w2l, 36864);
  gemm_kernel<false><<<1620, 256, 0, stream>>>(
      ao, w2h, w2l, b2, nullptr, nullptr, nullptr, nullptr, nullptr, nullptr, out);
}

// Round 5
// 406.749 us; speedup vs baseline: 2.4945x; 1.2382x over previous
//
#include <hip/hip_runtime.h>
#include <cstdint>
#include <cstddef>

// EarthAttention3D (Pangu-Weather): NW=720, L=144, DIM=192, H=6, hd=32
// All matmuls MFMA 16x16x32 bf16, split-bf16 (a = hi+lo; a*b ~= hh+hl+lh).
// MFMA layouts (validated rounds 2-4 here): A/B row-major [m|n][k], row =
// lane&15, k = (lane>>4)*8 + t. C/D: col(n) = lane&15, row(m) = (lane>>4)*4+reg.
//
// attn v3: swapped QK^T (S^T = mfma(K, Q)) -> lane holds S for ONE i.
// Softmax fully in-register (shfl_xor 16/32). P packed hi/lo in regs; PV
// A-frags built via tiny per-wave LDS scratch (aliases dead K region).
// Bias table pre-transposed into d_out (dead until proj) for coalesced fill.

using short8 = __attribute__((ext_vector_type(8))) short;
using f32x4  = __attribute__((ext_vector_type(4))) float;

constexpr int kNW = 720;
constexpr float kScale = 0.17677669529663687f;  // 32^-0.5
constexpr size_t kQKVElems = (size_t)kNW * 6 * 144 * 32;  // 19,906,560

__device__ __forceinline__ ushort bf16_rne(float f) {
  uint u = __builtin_bit_cast(uint, f);
  return (ushort)((u + 0x7FFFu + ((u >> 16) & 1u)) >> 16);
}
__device__ __forceinline__ float bf16_to_f(ushort h) {
  uint u = ((uint)h) << 16;
  return __builtin_bit_cast(float, u);
}

// ---------------------------------------------------------------------------
// prep: fp32 -> (hi,lo) bf16 planes.
// ---------------------------------------------------------------------------
__global__ __launch_bounds__(256) void prep_kernel(
    const float* __restrict__ src, ushort* __restrict__ dh,
    ushort* __restrict__ dl, int n)
{
  const int i = blockIdx.x * 256 + threadIdx.x;
  if (i < n) {
    const float f = src[i];
    const ushort h = bf16_rne(f);
    dh[i] = h;
    dl[i] = bf16_rne(f - bf16_to_f(h));
  }
}

// ---------------------------------------------------------------------------
// btT: transpose bias_table (3312,1440) -> (1440,3312) so attn's per-block
// Bs fill is contiguous. 48x48 LDS tiles; 3312=69*48, 1440=30*48.
// ---------------------------------------------------------------------------
__global__ __launch_bounds__(256) void btT_kernel(
    const float* __restrict__ bt, float* __restrict__ btT)
{
  __shared__ float T[48][49];
  const int pb = (blockIdx.x % 69) * 48;   // pos-tile
  const int bb = (blockIdx.x / 69) * 48;   // bth-tile
  const int tid = threadIdx.x;
  for (int f = tid; f < 2304; f += 256) {
    const int r = f / 48, c = f % 48;      // r = pos-local, c = bth-local
    T[r][c] = bt[(size_t)(pb + r) * 1440 + bb + c];
  }
  __syncthreads();
  for (int f = tid; f < 2304; f += 256) {
    const int r = f % 48, c = f / 48;      // coalesced in pos
    btT[(size_t)(bb + c) * 3312 + pb + r] = T[r][c];
  }
}

// ---------------------------------------------------------------------------
// GEMM: out[M,N] = X[M,192] @ W[N,192]^T + bias. BM=64, BN=192, BK=32.
// (unchanged from round 4)
// ---------------------------------------------------------------------------
template <bool IS_QKV>
__global__ __launch_bounds__(256) void gemm_kernel(
    const float* __restrict__ X, const ushort* __restrict__ Wh,
    const ushort* __restrict__ Wl, const float* __restrict__ bias,
    ushort* __restrict__ o0, ushort* __restrict__ o1, ushort* __restrict__ o2,
    ushort* __restrict__ o3, ushort* __restrict__ o4, ushort* __restrict__ o5,
    float* __restrict__ fout)
{
  __shared__ ushort Ah[64][40], Al[64][40];
  __shared__ ushort Bh[192][40], Bl[192][40];

  const int bid = blockIdx.x;
  const int mtile = IS_QKV ? bid / 3 : bid;
  const int col0  = IS_QKV ? (bid % 3) * 192 : 0;
  const int row0 = mtile * 64;
  const int tid = threadIdx.x;
  const int wv = tid >> 6;
  const int lane = tid & 63;
  const int rr = lane & 15;
  const int kg = lane >> 4;
  const int nbase = wv * 48;

  f32x4 acc[4][3];
#pragma unroll
  for (int a = 0; a < 4; ++a)
#pragma unroll
    for (int b = 0; b < 3; ++b) acc[a][b] = (f32x4){0.f, 0.f, 0.f, 0.f};

  for (int kc = 0; kc < 192; kc += 32) {
#pragma unroll
    for (int u = 0; u < 2; ++u) {
      const int sl = tid * 2 + u;
      const int r = sl >> 3, s = sl & 7;
      float4 xv = *(const float4*)&X[(size_t)(row0 + r) * 192 + kc + s * 4];
      ushort4 hv, lv;
      hv.x = bf16_rne(xv.x); lv.x = bf16_rne(xv.x - bf16_to_f(hv.x));
      hv.y = bf16_rne(xv.y); lv.y = bf16_rne(xv.y - bf16_to_f(hv.y));
      hv.z = bf16_rne(xv.z); lv.z = bf16_rne(xv.z - bf16_to_f(hv.z));
      hv.w = bf16_rne(xv.w); lv.w = bf16_rne(xv.w - bf16_to_f(hv.w));
      *(ushort4*)&Ah[r][s * 4] = hv;
      *(ushort4*)&Al[r][s * 4] = lv;
    }
#pragma unroll
    for (int u = 0; u < 6; ++u) {
      const int sl = tid + u * 256;
      const int n = sl >> 3, s = sl & 7;
      const size_t g = (size_t)(col0 + n) * 192 + kc + s * 4;
      *(uint2*)&Bh[n][s * 4] = *(const uint2*)&Wh[g];
      *(uint2*)&Bl[n][s * 4] = *(const uint2*)&Wl[g];
    }
    __syncthreads();

    short8 ah[4], al_[4], bh[3], bl[3];
#pragma unroll
    for (int mt = 0; mt < 4; ++mt) {
      ah[mt]  = *(const short8*)&Ah[mt * 16 + rr][kg * 8];
      al_[mt] = *(const short8*)&Al[mt * 16 + rr][kg * 8];
    }
#pragma unroll
    for (int nt = 0; nt < 3; ++nt) {
      bh[nt] = *(const short8*)&Bh[nbase + nt * 16 + rr][kg * 8];
      bl[nt] = *(const short8*)&Bl[nbase + nt * 16 + rr][kg * 8];
    }
#pragma unroll
    for (int mt = 0; mt < 4; ++mt)
#pragma unroll
      for (int nt = 0; nt < 3; ++nt) {
        acc[mt][nt] = __builtin_amdgcn_mfma_f32_16x16x32_bf16(ah[mt],  bh[nt], acc[mt][nt], 0, 0, 0);
        acc[mt][nt] = __builtin_amdgcn_mfma_f32_16x16x32_bf16(ah[mt],  bl[nt], acc[mt][nt], 0, 0, 0);
        acc[mt][nt] = __builtin_amdgcn_mfma_f32_16x16x32_bf16(al_[mt], bh[nt], acc[mt][nt], 0, 0, 0);
      }
    __syncthreads();
  }

  if (IS_QKV) {
    const int t = col0 / 192;
    ushort* dh = (t == 0) ? o0 : (t == 1) ? o2 : o4;
    ushort* dl = (t == 0) ? o1 : (t == 1) ? o3 : o5;
    const float sc = (t == 0) ? kScale : 1.0f;
#pragma unroll
    for (int nt = 0; nt < 3; ++nt) {
      const int c0 = nbase + nt * 16;
      const int hh = c0 >> 5;
      const int d0 = (c0 & 31) + rr;
      const float bcol = bias[col0 + c0 + rr];
#pragma unroll
      for (int mt = 0; mt < 4; ++mt)
#pragma unroll
        for (int reg = 0; reg < 4; ++reg) {
          const int grow = row0 + mt * 16 + kg * 4 + reg;
          const int w = grow / 144;
          const int l = grow % 144;
          const float vv = (acc[mt][nt][reg] + bcol) * sc;
          const ushort hv = bf16_rne(vv);
          const size_t idx = (((size_t)(w * 6 + hh)) * 144 + l) * 32 + d0;
          dh[idx] = hv;
          dl[idx] = bf16_rne(vv - bf16_to_f(hv));
        }
    }
  } else {
#pragma unroll
    for (int nt = 0; nt < 3; ++nt) {
      const int c = nbase + nt * 16 + rr;
      const float bcol = bias[c];
#pragma unroll
      for (int mt = 0; mt < 4; ++mt)
#pragma unroll
        for (int reg = 0; reg < 4; ++reg) {
          const int grow = row0 + mt * 16 + kg * 4 + reg;
          fout[(size_t)grow * 192 + c] = acc[mt][nt][reg] + bcol;
        }
    }
  }
}

// ---------------------------------------------------------------------------
// attn v3: one block per (w,h), 576 thr = 9 waves; wave owns i-strip of 16.
// LDS 57.8 KB -> target 2 blocks/CU. Two barriers total.
// Phase 1: S^T tiles = mfma(K_frag, Q_frag); bias/mask added in regs.
// Phase 2: in-register softmax (shfl_xor 16/32), pack P hi/lo words.
// Phase 3: per ks (j-32-chunk): 16x32 per-wave LDS transpose (aliases K),
//          PV = mfma(P, Vt) straight -> coalesced ao stores.
// ---------------------------------------------------------------------------
__global__ __launch_bounds__(576, 5) void attn_kernel(
    const ushort* __restrict__ qh, const ushort* __restrict__ ql,
    const ushort* __restrict__ kh, const ushort* __restrict__ kl,
    const ushort* __restrict__ vh, const ushort* __restrict__ vl,
    const float* __restrict__ mask, const float* __restrict__ btT,
    float* __restrict__ ao)
{
  __shared__ ushort Ks_[2][144][40];   // K hi/lo; aliased by P-scratch in PV
  __shared__ ushort Vt[2][32][168];    // V^T hi/lo [d][j], j in [0,160) used
  __shared__ float Bs[3312];

  const int bid = blockIdx.x;
  const int wid = (bid & 7) * 540 + (bid >> 3);  // bijective XCD remap
  const int w = wid / 6, h = wid % 6;
  const int tid = threadIdx.x;
  const int wave = tid >> 6;   // 0..8
  const int lane = tid & 63;
  const int rr = lane & 15;
  const int kg = lane >> 4;
  const size_t base = (size_t)(w * 6 + h) * 4608;
  const float* mrow = mask + (size_t)w * 20736;
  const float* brow = btT + (size_t)((w % 240) * 6 + h) * 3312;

  // --- stage K hi/lo, V^T hi/lo, Bs (coalesced) ---
  for (int f = tid; f < 1152; f += 576) {
    const int l = f >> 3, d0 = (f & 7) * 4;
    *(uint2*)&Ks_[0][l][d0] = *(const uint2*)&kh[base + l * 32 + d0];
    *(uint2*)&Ks_[1][l][d0] = *(const uint2*)&kl[base + l * 32 + d0];
    const ushort4 a = *(const ushort4*)&vh[base + l * 32 + d0];
    Vt[0][d0 + 0][l] = a.x; Vt[0][d0 + 1][l] = a.y;
    Vt[0][d0 + 2][l] = a.z; Vt[0][d0 + 3][l] = a.w;
    const ushort4 b = *(const ushort4*)&vl[base + l * 32 + d0];
    Vt[1][d0 + 0][l] = b.x; Vt[1][d0 + 1][l] = b.y;
    Vt[1][d0 + 2][l] = b.z; Vt[1][d0 + 3][l] = b.w;
  }
  if (tid < 512) {  // zero-pad Vt j in [144,160) (0 x junk = NaN guard)
    const int d = tid >> 4, j = 144 + (tid & 15);
    Vt[0][d][j] = 0;
    Vt[1][d][j] = 0;
  }
  for (int p = tid; p < 3312; p += 576) Bs[p] = brow[p];
  __syncthreads();

  // --- Phase 1: S^T = K . Q^T (+bias+mask). Lane: i = i0+rr fixed,
  //     j = 16*jt + 4*kg + reg. Q B-frags straight from global. ---
  const int i0 = wave * 16;
  const int i = i0 + rr;
  const short8 qbh = *(const short8*)&qh[base + (size_t)i * 32 + kg * 8];
  const short8 qbl = *(const short8*)&ql[base + (size_t)i * 32 + kg * 8];
  const int pi = 828 * (i / 72) + 23 * ((i / 12) % 6) + (i % 12) + 11;

  f32x4 acc[9];
#pragma unroll
  for (int jt = 0; jt < 9; ++jt) {
    const short8 kah = *(const short8*)&Ks_[0][jt * 16 + rr][kg * 8];
    const short8 kal = *(const short8*)&Ks_[1][jt * 16 + rr][kg * 8];
    f32x4 c = (f32x4){0.f, 0.f, 0.f, 0.f};
    c = __builtin_amdgcn_mfma_f32_16x16x32_bf16(kah, qbh, c, 0, 0, 0);
    c = __builtin_amdgcn_mfma_f32_16x16x32_bf16(kah, qbl, c, 0, 0, 0);
    c = __builtin_amdgcn_mfma_f32_16x16x32_bf16(kal, qbh, c, 0, 0, 0);
    const int jb = jt * 16 + kg * 4;  // 4-aligned: pos affine over the run
    const int pjb = 1656 * (jb / 72) + 138 * ((jb / 12) % 6) - (jb % 12);
    const float4 mv = *(const float4*)&mrow[(size_t)i * 144 + jb];
    const int bb = pi + pjb;
    c[0] += Bs[bb]     + mv.x;
    c[1] += Bs[bb - 1] + mv.y;
    c[2] += Bs[bb - 2] + mv.z;
    c[3] += Bs[bb - 3] + mv.w;
    acc[jt] = c;
  }

  // --- Phase 2: softmax over j (in regs; lanes {rr,rr+16,rr+32,rr+48} share i)
  float m = -1e30f;
#pragma unroll
  for (int jt = 0; jt < 9; ++jt)
    m = fmaxf(m, fmaxf(fmaxf(acc[jt][0], acc[jt][1]),
                       fmaxf(acc[jt][2], acc[jt][3])));
  m = fmaxf(m, __shfl_xor(m, 16));
  m = fmaxf(m, __shfl_xor(m, 32));
  float s = 0.f;
#pragma unroll
  for (int jt = 0; jt < 9; ++jt)
#pragma unroll
    for (int r = 0; r < 4; ++r) {
      acc[jt][r] = __expf(acc[jt][r] - m);
      s += acc[jt][r];
    }
  s += __shfl_xor(s, 16);
  s += __shfl_xor(s, 32);
  const float inv = 1.0f / s;

  uint wh_[10][2], wl_[10][2];  // jt 9 = zero pad (j in [144,160))
#pragma unroll
  for (int jt = 0; jt < 9; ++jt)
#pragma unroll
    for (int u = 0; u < 2; ++u) {
      const float p0 = acc[jt][2 * u] * inv, p1 = acc[jt][2 * u + 1] * inv;
      const ushort h0 = bf16_rne(p0), h1 = bf16_rne(p1);
      const ushort l0 = bf16_rne(p0 - bf16_to_f(h0));
      const ushort l1 = bf16_rne(p1 - bf16_to_f(h1));
      wh_[jt][u] = (uint)h0 | ((uint)h1 << 16);
      wl_[jt][u] = (uint)l0 | ((uint)l1 << 16);
    }
  wh_[9][0] = 0; wh_[9][1] = 0; wl_[9][0] = 0; wl_[9][1] = 0;

  __syncthreads();  // all K reads done -> scratch (aliases K) is safe

  // --- Phase 3: PV. Per-wave scratch: hi[16][40] + lo[16][40] ushort = 2560 B.
  uint* scrw = (uint*)((ushort*)&Ks_[0][0][0] + wave * 1280);  // dwords; row=20
  f32x4 oacc[2] = {(f32x4){0.f, 0.f, 0.f, 0.f}, (f32x4){0.f, 0.f, 0.f, 0.f}};
#pragma unroll
  for (int ks = 0; ks < 5; ++ks) {
    const int jtA = 2 * ks, jtB = 2 * ks + 1;
    // write lane's j-slice (transpose across kg within same rr)
    *(uint2*)&scrw[rr * 20 + 2 * kg]           = make_uint2(wh_[jtA][0], wh_[jtA][1]);
    *(uint2*)&scrw[rr * 20 + 8 + 2 * kg]       = make_uint2(wh_[jtB][0], wh_[jtB][1]);
    *(uint2*)&scrw[320 + rr * 20 + 2 * kg]     = make_uint2(wl_[jtA][0], wl_[jtA][1]);
    *(uint2*)&scrw[320 + rr * 20 + 8 + 2 * kg] = make_uint2(wl_[jtB][0], wl_[jtB][1]);
    asm volatile("s_waitcnt lgkmcnt(0)" ::: "memory");
    const ushort* scr = (const ushort*)scrw;
    const short8 pfh = *(const short8*)&scr[rr * 40 + kg * 8];
    const short8 pfl = *(const short8*)&scr[640 + rr * 40 + kg * 8];
#pragma unroll
    for (int dt = 0; dt < 2; ++dt) {
      const short8 vfh = *(const short8*)&Vt[0][dt * 16 + rr][ks * 32 + kg * 8];
      const short8 vfl = *(const short8*)&Vt[1][dt * 16 + rr][ks * 32 + kg * 8];
      oacc[dt] = __builtin_amdgcn_mfma_f32_16x16x32_bf16(pfh, vfh, oacc[dt], 0, 0, 0);
      oacc[dt] = __builtin_amdgcn_mfma_f32_16x16x32_bf16(pfh, vfl, oacc[dt], 0, 0, 0);
      oacc[dt] = __builtin_amdgcn_mfma_f32_16x16x32_bf16(pfl, vfh, oacc[dt], 0, 0, 0);
    }
  }

  // stores: C/D row(m)=i-local=kg*4+reg, col(n)=d-local=rr -> coalesced in rr
#pragma unroll
  for (int dt = 0; dt < 2; ++dt)
#pragma unroll
    for (int r = 0; r < 4; ++r)
      ao[(size_t)(w * 144 + i0 + kg * 4 + r) * 192 + h * 32 + dt * 16 + rr] =
          oacc[dt][r];
}

// ---------------------------------------------------------------------------
extern "C" void kernel_launch(void* const* d_in, const int* in_sizes, int n_in,
                              void* d_out, int out_size, void* d_ws, size_t ws_size,
                              hipStream_t stream)
{
  const float* x    = (const float*)d_in[0];  // (720,144,192)
  const float* mask = (const float*)d_in[1];  // (720,144,144)
  const float* w1   = (const float*)d_in[2];  // (576,192)
  const float* b1   = (const float*)d_in[3];  // (576,)
  const float* w2   = (const float*)d_in[4];  // (192,192)
  const float* b2   = (const float*)d_in[5];  // (192,)
  const float* bt   = (const float*)d_in[6];  // (3312,240,6)
  float* out = (float*)d_out;

  // ws layout (318,504,960 B total):
  ushort* qh = (ushort*)d_ws;
  ushort* ql = qh + kQKVElems;
  ushort* kh = ql + kQKVElems;
  ushort* kl = kh + kQKVElems;
  ushort* vh = kl + kQKVElems;
  ushort* vl = vh + kQKVElems;
  float*  ao = (float*)(vl + kQKVElems);
  // w1 planes in dead ao region (qkv reads them before attn writes ao)
  ushort* w1h = (ushort*)ao;
  ushort* w1l = w1h + 110592;
  // w2 planes in dead qh region (prep2 runs after attn)
  ushort* w2h = qh;
  ushort* w2l = w2h + 36864;
  // transposed bias table in dead d_out region (proj overwrites at the end)
  float* btT = out;  // (1440, 3312) = 19.1 MB < 79.6 MB

  btT_kernel<<<69 * 30, 256, 0, stream>>>(bt, btT);
  prep_kernel<<<432, 256, 0, stream>>>(w1, w1h, w1l, 110592);
  gemm_kernel<true><<<1620 * 3, 256, 0, stream>>>(
      x, w1h, w1l, b1, qh, ql, kh, kl, vh, vl, nullptr);
  attn_kernel<<<4320, 576, 0, stream>>>(qh, ql, kh, kl, vh, vl, mask, btT, ao);
  prep_kernel<<<144, 256, 0, stream>>>(w2, w2h, w2l, 36864);
  gemm_kernel<false><<<1620, 256, 0, stream>>>(
      ao, w2h, w2l, b2, nullptr, nullptr, nullptr, nullptr, nullptr, nullptr, out);
}